// Round 1
// baseline (634.662 us; speedup 1.0000x reference)
//
#include <hip/hip_runtime.h>
#include <stdint.h>

#define B_ 2
#define S_ 2048
#define D_ 1024
#define H_ 16
#define DH 64
#define BS_ (B_*S_)
#define QBLK 64
#define KBLK 128

typedef unsigned short u16;
typedef __attribute__((ext_vector_type(8))) __bf16 bf16x8;
typedef __attribute__((ext_vector_type(4))) float f32x4;

__device__ __forceinline__ u16 f2bf(float f){
  unsigned u = __float_as_uint(f);
  u += 0x7fffu + ((u >> 16) & 1u);   // RNE
  return (u16)(u >> 16);
}

union pk8 { u16 a[8]; uint4 v; };

// ---------------- GEMM: C[M,N] = A[M,K] @ W[N,K]^T + bias ----------------
// ABF16: A is bf16 (u16). else A is fp32 (converted during LDS staging).
// W is always fp32 (converted during staging). BF16OUT: C stored as bf16.
template<int BF16OUT, int ABF16>
__global__ __launch_bounds__(256) void gemm_bt_kernel(
    const void* __restrict__ Ap, const float* __restrict__ W,
    const float* __restrict__ bias, void* __restrict__ Cout,
    int M, int N, int K)
{
  const int bn = blockIdx.x, bm = blockIdx.y;
  const int tid = threadIdx.x, wv = tid >> 6, lane = tid & 63;
  const int g = lane >> 4, c16 = lane & 15;
  const int wr = wv >> 1, wc = wv & 1;

  __shared__ alignas(16) u16 at[128][64];
  __shared__ alignas(16) u16 btl[128][64];

  f32x4 acc[4][4];
  #pragma unroll
  for (int mi = 0; mi < 4; ++mi)
    #pragma unroll
    for (int ni = 0; ni < 4; ++ni) acc[mi][ni] = (f32x4){0.f,0.f,0.f,0.f};

  for (int kt = 0; kt < K; kt += 64){
    #pragma unroll
    for (int cc = 0; cc < 4; ++cc){
      const int eo = (tid + cc*256)*8, r = eo >> 6, c = eo & 63;
      if (ABF16){
        *(bf16x8*)((u16*)at + eo) =
            *(const bf16x8*)((const u16*)Ap + (size_t)(bm*128 + r)*K + kt + c);
      } else {
        const float* s = (const float*)Ap + (size_t)(bm*128 + r)*K + kt + c;
        float4 v0 = *(const float4*)s, v1 = *(const float4*)(s + 4);
        pk8 p;
        p.a[0]=f2bf(v0.x); p.a[1]=f2bf(v0.y); p.a[2]=f2bf(v0.z); p.a[3]=f2bf(v0.w);
        p.a[4]=f2bf(v1.x); p.a[5]=f2bf(v1.y); p.a[6]=f2bf(v1.z); p.a[7]=f2bf(v1.w);
        *(uint4*)((u16*)at + eo) = p.v;
      }
      {
        const float* s = W + (size_t)(bn*128 + r)*K + kt + c;
        float4 v0 = *(const float4*)s, v1 = *(const float4*)(s + 4);
        pk8 p;
        p.a[0]=f2bf(v0.x); p.a[1]=f2bf(v0.y); p.a[2]=f2bf(v0.z); p.a[3]=f2bf(v0.w);
        p.a[4]=f2bf(v1.x); p.a[5]=f2bf(v1.y); p.a[6]=f2bf(v1.z); p.a[7]=f2bf(v1.w);
        *(uint4*)((u16*)btl + eo) = p.v;
      }
    }
    __syncthreads();
    #pragma unroll
    for (int ks = 0; ks < 2; ++ks){
      bf16x8 af[4], bfr[4];
      #pragma unroll
      for (int mi = 0; mi < 4; ++mi)
        af[mi] = *(const bf16x8*)(&at[wr*64 + mi*16 + c16][ks*32 + g*8]);
      #pragma unroll
      for (int ni = 0; ni < 4; ++ni)
        bfr[ni] = *(const bf16x8*)(&btl[wc*64 + ni*16 + c16][ks*32 + g*8]);
      #pragma unroll
      for (int mi = 0; mi < 4; ++mi)
        #pragma unroll
        for (int ni = 0; ni < 4; ++ni)
          acc[mi][ni] = __builtin_amdgcn_mfma_f32_16x16x32_bf16(
              af[mi], bfr[ni], acc[mi][ni], 0, 0, 0);
    }
    __syncthreads();
  }

  #pragma unroll
  for (int mi = 0; mi < 4; ++mi){
    const int row0 = bm*128 + wr*64 + mi*16 + g*4;
    #pragma unroll
    for (int ni = 0; ni < 4; ++ni){
      const int col = bn*128 + wc*64 + ni*16 + c16;
      const float bb = bias[col];
      #pragma unroll
      for (int r = 0; r < 4; ++r){
        float v = acc[mi][ni][r] + bb;
        if (BF16OUT) ((u16*)Cout)[(size_t)(row0 + r)*N + col] = f2bf(v);
        else        ((float*)Cout)[(size_t)(row0 + r)*N + col] = v;
      }
    }
  }
}

// ---------------- per-head V transpose: vtb[bh][d][k] = vb[bh][k][d] ----------------
__global__ __launch_bounds__(256) void vtrans_kernel(
    const u16* __restrict__ vb, u16* __restrict__ vtb)
{
  const int kt = blockIdx.x, bh = blockIdx.y;
  __shared__ alignas(16) u16 t[64][80];   // padded stride
  const int tid = threadIdx.x;
  const u16* slab = vb + (size_t)bh*S_*DH + (size_t)kt*64*DH;
  #pragma unroll
  for (int j = 0; j < 2; ++j){
    const int r = j*32 + (tid >> 3), c = (tid & 7)*8;
    *(bf16x8*)(&t[r][c]) = *(const bf16x8*)(slab + (size_t)r*DH + c);
  }
  __syncthreads();
  u16* oslab = vtb + (size_t)bh*DH*S_ + (size_t)kt*64;
  #pragma unroll
  for (int j = 0; j < 2; ++j){
    const int dd = j*32 + (tid >> 3), k8 = (tid & 7)*8;
    pk8 u;
    #pragma unroll
    for (int e = 0; e < 8; ++e) u.a[e] = t[k8 + e][dd];
    *(uint4*)(oslab + (size_t)dd*S_ + k8) = u.v;
  }
}

// ---------------- fused attention per (bh, q-block of 64) ----------------
// pass1: row sums of exp(S/32); pass2: recompute S, write dist, PV accumulate.
__global__ __launch_bounds__(256) void attn_kernel(
    const u16* __restrict__ qb, const u16* __restrict__ kb,
    const u16* __restrict__ vtb, float* __restrict__ dist,
    u16* __restrict__ attnb)
{
  const int qblk = blockIdx.x, bh = blockIdx.y;
  const int tid = threadIdx.x, w = tid >> 6, lane = tid & 63;
  const int g = lane >> 4, c16 = lane & 15;

  __shared__ alignas(16) u16 klds[KBLK][DH];     // 16 KB
  __shared__ alignas(16) u16 vtlds[DH][KBLK];    // 16 KB
  __shared__ alignas(16) u16 plds[4][16][KBLK];  // 16 KB

  const u16* qsl = qb  + (size_t)bh*S_*DH;
  const u16* ksl = kb  + (size_t)bh*S_*DH;
  const u16* vsl = vtb + (size_t)bh*DH*S_;

  const int qr0 = qblk*QBLK + w*16;
  bf16x8 qf[2];
  #pragma unroll
  for (int ks = 0; ks < 2; ++ks)
    qf[ks] = *(const bf16x8*)(qsl + (size_t)(qr0 + c16)*DH + ks*32 + g*8);

  const float sc = 1.0f/32.0f;
  float sums[4] = {0.f,0.f,0.f,0.f};

  // ---- pass 1: denominators ----
  for (int kt = 0; kt < S_; kt += KBLK){
    #pragma unroll
    for (int cc = 0; cc < 4; ++cc){
      const int eo = (tid + cc*256)*8, r = eo >> 6, c = eo & 63;
      *(bf16x8*)((u16*)klds + eo) =
          *(const bf16x8*)(ksl + (size_t)(kt + r)*DH + c);
    }
    __syncthreads();
    for (int n = 0; n < 8; ++n){
      f32x4 s = (f32x4){0.f,0.f,0.f,0.f};
      #pragma unroll
      for (int ks = 0; ks < 2; ++ks){
        bf16x8 kf = *(const bf16x8*)(&klds[n*16 + c16][ks*32 + g*8]);
        s = __builtin_amdgcn_mfma_f32_16x16x32_bf16(qf[ks], kf, s, 0, 0, 0);
      }
      #pragma unroll
      for (int r = 0; r < 4; ++r) sums[r] += __expf(s[r]*sc);
    }
    __syncthreads();
  }
  #pragma unroll
  for (int m = 1; m < 16; m <<= 1)
    #pragma unroll
    for (int r = 0; r < 4; ++r) sums[r] += __shfl_xor(sums[r], m, 64);
  float inv[4];
  #pragma unroll
  for (int r = 0; r < 4; ++r) inv[r] = 1.0f/sums[r];

  f32x4 oacc[4];
  #pragma unroll
  for (int n2 = 0; n2 < 4; ++n2) oacc[n2] = (f32x4){0.f,0.f,0.f,0.f};

  float* drow = dist + ((size_t)bh*S_ + qblk*QBLK + w*16 + g*4)*S_;

  // ---- pass 2: dist write + PV ----
  for (int kt = 0; kt < S_; kt += KBLK){
    #pragma unroll
    for (int cc = 0; cc < 4; ++cc){
      const int eo = (tid + cc*256)*8;
      { const int r = eo >> 6, c = eo & 63;
        *(bf16x8*)((u16*)klds + eo) =
            *(const bf16x8*)(ksl + (size_t)(kt + r)*DH + c); }
      { const int r = eo >> 7, c = eo & 127;
        *(bf16x8*)((u16*)vtlds + eo) =
            *(const bf16x8*)(vsl + (size_t)r*S_ + kt + c); }
    }
    __syncthreads();
    for (int n = 0; n < 8; ++n){
      f32x4 s = (f32x4){0.f,0.f,0.f,0.f};
      #pragma unroll
      for (int ks = 0; ks < 2; ++ks){
        bf16x8 kf = *(const bf16x8*)(&klds[n*16 + c16][ks*32 + g*8]);
        s = __builtin_amdgcn_mfma_f32_16x16x32_bf16(qf[ks], kf, s, 0, 0, 0);
      }
      #pragma unroll
      for (int r = 0; r < 4; ++r){
        float p = __expf(s[r]*sc) * inv[r];
        drow[(size_t)r*S_ + kt + n*16 + c16] = p;
        plds[w][g*4 + r][n*16 + c16] = f2bf(p);
      }
    }
    // PV: attn += P @ V  (A = P rows, B = V via VT rows)
    #pragma unroll
    for (int kc = 0; kc < 4; ++kc){
      bf16x8 pf = *(const bf16x8*)(&plds[w][c16][kc*32 + g*8]);
      #pragma unroll
      for (int n2 = 0; n2 < 4; ++n2){
        bf16x8 vf = *(const bf16x8*)(&vtlds[n2*16 + c16][kc*32 + g*8]);
        oacc[n2] = __builtin_amdgcn_mfma_f32_16x16x32_bf16(pf, vf, oacc[n2], 0, 0, 0);
      }
    }
    __syncthreads();
  }

  u16* asl = attnb + (size_t)bh*S_*DH;
  #pragma unroll
  for (int n2 = 0; n2 < 4; ++n2)
    #pragma unroll
    for (int r = 0; r < 4; ++r)
      asl[(size_t)(qr0 + g*4 + r)*DH + n2*16 + c16] = f2bf(oacc[n2][r]);
}

// ---------------- launch ----------------
extern "C" void kernel_launch(void* const* d_in, const int* in_sizes, int n_in,
                              void* d_out, int out_size, void* d_ws, size_t ws_size,
                              hipStream_t stream)
{
  const float* Q  = (const float*)d_in[0];
  const float* K  = (const float*)d_in[1];
  const float* V  = (const float*)d_in[2];
  const float* WQ = (const float*)d_in[3]; const float* bQ = (const float*)d_in[4];
  const float* WK = (const float*)d_in[5]; const float* bK = (const float*)d_in[6];
  const float* WV = (const float*)d_in[7]; const float* bV = (const float*)d_in[8];
  const float* WO = (const float*)d_in[9]; const float* bO = (const float*)d_in[10];

  float* out  = (float*)d_out;
  float* dist = out + (size_t)BS_*D_;          // outputs concatenated: out, dist

  const size_t XS = (size_t)BS_*D_;            // 4194304 elements
  char* ws = (char*)d_ws;
  u16* qb    = (u16*)(ws);
  u16* kb    = (u16*)(ws + 2*XS);
  u16* vb    = (u16*)(ws + 4*XS);
  u16* vtb   = (u16*)(ws + 6*XS);
  u16* attnb = (u16*)(ws + 8*XS);              // total 40 MB of ws

  dim3 gp(D_/128, BS_/128);                    // (8, 32)
  gemm_bt_kernel<1,0><<<gp, 256, 0, stream>>>(Q, WQ, bQ, qb, BS_, D_, D_);
  gemm_bt_kernel<1,0><<<gp, 256, 0, stream>>>(K, WK, bK, kb, BS_, D_, D_);
  gemm_bt_kernel<1,0><<<gp, 256, 0, stream>>>(V, WV, bV, vb, BS_, D_, D_);

  vtrans_kernel<<<dim3(S_/64, B_*H_), 256, 0, stream>>>(vb, vtb);

  attn_kernel<<<dim3(S_/QBLK, B_*H_), 256, 0, stream>>>(qb, kb, vtb, dist, attnb);

  gemm_bt_kernel<0,1><<<gp, 256, 0, stream>>>(attnb, WO, bO, out, BS_, D_, D_);
}

// Round 2
// 316.681 us; speedup vs baseline: 2.0041x; 2.0041x over previous
//
#include <hip/hip_runtime.h>
#include <stdint.h>

#define B_ 2
#define S_ 2048
#define D_ 1024
#define H_ 16
#define DH 64
#define BS_ (B_*S_)
#define QBLK 64
#define KBLK 128

typedef unsigned short u16;
typedef __attribute__((ext_vector_type(8))) __bf16 bf16x8;
typedef __attribute__((ext_vector_type(4))) float f32x4;

__device__ __forceinline__ u16 f2bf(float f){
  unsigned u = __float_as_uint(f);
  u += 0x7fffu + ((u >> 16) & 1u);   // RNE
  return (u16)(u >> 16);
}

union pk8 { u16 a[8]; uint4 v; };

typedef __attribute__((address_space(1))) const unsigned gas_u32;
typedef __attribute__((address_space(3))) unsigned las_u32;
__device__ __forceinline__ void gload16(const void* g, void* l){
  __builtin_amdgcn_global_load_lds((gas_u32*)g, (las_u32*)l, 16, 0, 0);
}

// ---------------- fp32 -> bf16 bulk convert (7 tensors) ----------------
__global__ __launch_bounds__(256) void cvt_kernel(
    const float* __restrict__ Q, const float* __restrict__ K, const float* __restrict__ V,
    const float* __restrict__ WQ, const float* __restrict__ WK,
    const float* __restrict__ WV, const float* __restrict__ WO,
    u16* Qc, u16* Kc, u16* Vc, u16* wq, u16* wk, u16* wv, u16* wo)
{
  const int b = blockIdx.x;
  const float* s; u16* d; size_t off;
  if (b < 6144){
    int t = b >> 11;
    s = t==0?Q:(t==1?K:V); d = t==0?Qc:(t==1?Kc:Vc);
    off = (size_t)(b & 2047)*2048;
  } else {
    int t = (b - 6144) >> 9;
    s = t==0?WQ:(t==1?WK:(t==2?WV:WO)); d = t==0?wq:(t==1?wk:(t==2?wv:wo));
    off = (size_t)((b - 6144) & 511)*2048;
  }
  const float* sp = s + off + (size_t)threadIdx.x*8;
  float4 v0 = *(const float4*)sp, v1 = *(const float4*)(sp + 4);
  pk8 p;
  p.a[0]=f2bf(v0.x); p.a[1]=f2bf(v0.y); p.a[2]=f2bf(v0.z); p.a[3]=f2bf(v0.w);
  p.a[4]=f2bf(v1.x); p.a[5]=f2bf(v1.y); p.a[6]=f2bf(v1.z); p.a[7]=f2bf(v1.w);
  *(uint4*)(d + off + (size_t)threadIdx.x*8) = p.v;
}

// ---------------- GEMM: C[M,N] = A[M,K](bf16) @ W[N,K]^T(bf16) + bias ----------------
// BM=128, BN=64, BK=64, 256 threads (4 waves, 2x2), global_load_lds staging,
// XOR-swizzled LDS (slot = granule ^ (row&7)), linear dest + inverse-swz source.
template<int F32OUT>
__global__ __launch_bounds__(256) void gemm_kernel(
    const u16* __restrict__ A, const u16* __restrict__ Wt,
    const float* __restrict__ bias, void* __restrict__ Cout,
    int M, int N, int K)
{
  const int bn = blockIdx.x, bm = blockIdx.y;
  const int tid = threadIdx.x, w = tid >> 6, lane = tid & 63;
  const int g = lane >> 4, c16 = lane & 15;
  const int wr = w >> 1, wc = w & 1;
  const int lr = lane >> 3, lg = lane & 7;
  const int gsrc = lg ^ (lr & 7);          // inverse-swizzled source granule

  __shared__ alignas(16) u16 at[128*64];
  __shared__ alignas(16) u16 bt[64*64];

  f32x4 acc[4][2];
  #pragma unroll
  for (int mi = 0; mi < 4; ++mi)
    #pragma unroll
    for (int ni = 0; ni < 2; ++ni) acc[mi][ni] = (f32x4){0.f,0.f,0.f,0.f};

  for (int kt = 0; kt < K; kt += 64){
    #pragma unroll
    for (int i = 0; i < 4; ++i){
      const int r = w*32 + i*8 + lr;
      gload16(A + (size_t)(bm*128 + r)*K + kt + gsrc*8, at + (w*32 + i*8)*64);
    }
    #pragma unroll
    for (int i = 0; i < 2; ++i){
      const int r = w*16 + i*8 + lr;
      gload16(Wt + (size_t)(bn*64 + r)*K + kt + gsrc*8, bt + (w*16 + i*8)*64);
    }
    __syncthreads();
    #pragma unroll
    for (int ks = 0; ks < 2; ++ks){
      bf16x8 af[4], bfr[2];
      #pragma unroll
      for (int mi = 0; mi < 4; ++mi){
        const int row = wr*64 + mi*16 + c16;
        af[mi] = *(const bf16x8*)(at + row*64 + ((ks*4 + g) ^ (row & 7))*8);
      }
      #pragma unroll
      for (int ni = 0; ni < 2; ++ni){
        const int row = wc*32 + ni*16 + c16;
        bfr[ni] = *(const bf16x8*)(bt + row*64 + ((ks*4 + g) ^ (row & 7))*8);
      }
      #pragma unroll
      for (int mi = 0; mi < 4; ++mi)
        #pragma unroll
        for (int ni = 0; ni < 2; ++ni)
          acc[mi][ni] = __builtin_amdgcn_mfma_f32_16x16x32_bf16(
              af[mi], bfr[ni], acc[mi][ni], 0, 0, 0);
    }
    __syncthreads();
  }

  #pragma unroll
  for (int mi = 0; mi < 4; ++mi){
    const int row0 = bm*128 + wr*64 + mi*16 + g*4;
    #pragma unroll
    for (int ni = 0; ni < 2; ++ni){
      const int col = bn*64 + wc*32 + ni*16 + c16;
      const float bb = bias[col];
      #pragma unroll
      for (int r = 0; r < 4; ++r){
        float v = acc[mi][ni][r] + bb;
        if (F32OUT) ((float*)Cout)[(size_t)(row0 + r)*N + col] = v;
        else        ((u16*)Cout)[(size_t)(row0 + r)*N + col] = f2bf(v);
      }
    }
  }
}

// ---------------- per-head V transpose: vtb[bh][d][k] = vb[bh][k][d] ----------------
__global__ __launch_bounds__(256) void vtrans_kernel(
    const u16* __restrict__ vb, u16* __restrict__ vtb)
{
  const int kt = blockIdx.x, bh = blockIdx.y;
  __shared__ alignas(16) u16 t[64][80];
  const int tid = threadIdx.x;
  const u16* slab = vb + (size_t)bh*S_*DH + (size_t)kt*64*DH;
  #pragma unroll
  for (int j = 0; j < 2; ++j){
    const int r = j*32 + (tid >> 3), c = (tid & 7)*8;
    *(bf16x8*)(&t[r][c]) = *(const bf16x8*)(slab + (size_t)r*DH + c);
  }
  __syncthreads();
  u16* oslab = vtb + (size_t)bh*DH*S_ + (size_t)kt*64;
  #pragma unroll
  for (int j = 0; j < 2; ++j){
    const int dd = j*32 + (tid >> 3), k8 = (tid & 7)*8;
    pk8 u;
    #pragma unroll
    for (int e = 0; e < 8; ++e) u.a[e] = t[k8 + e][dd];
    *(uint4*)(oslab + (size_t)dd*S_ + k8) = u.v;
  }
}

// ---------------- fused attention, swapped-S (lane holds a q-row k-slice) --------
// pass1: row sums of exp(S/32); pass2: recompute S, float4 dist write, PV via MFMA.
// klds: [128][64] u16, slot = gi ^ (row&7)
// vtlds:[64][128] u16, slot = gi ^ (row&15)
// plds: [4][16][128] u16 (per-warp P, bf16), slot = gi ^ (qrow&15)
__global__ __launch_bounds__(256) void attn_kernel(
    const u16* __restrict__ qb, const u16* __restrict__ kb,
    const u16* __restrict__ vtb, float* __restrict__ dist,
    u16* __restrict__ attnb)
{
  const int qblk = blockIdx.x, bh = blockIdx.y;
  const int tid = threadIdx.x, w = tid >> 6, lane = tid & 63;
  const int g = lane >> 4, c16 = lane & 15;
  const int lr = lane >> 3, lg = lane & 7;
  const int gsrc = lg ^ (lr & 7);
  const int lr4 = lane >> 4, lg4 = lane & 15;

  __shared__ alignas(16) u16 klds[128*64];
  __shared__ alignas(16) u16 vtlds[64*128];
  __shared__ alignas(16) u16 plds[4*16*128];

  const u16* qsl = qb  + (size_t)bh*S_*DH;
  const u16* ksl = kb  + (size_t)bh*S_*DH;
  const u16* vsl = vtb + (size_t)bh*DH*S_;

  const int q0 = qblk*QBLK + w*16;
  bf16x8 qf[2];
  #pragma unroll
  for (int ks = 0; ks < 2; ++ks)
    qf[ks] = *(const bf16x8*)(qsl + (size_t)(q0 + c16)*DH + ks*32 + g*8);

  const float sc = 1.0f/32.0f;
  float sum = 0.f;

  // ---- pass 1: denominators (K tiles only) ----
  for (int kt = 0; kt < S_; kt += KBLK){
    #pragma unroll
    for (int i = 0; i < 4; ++i){
      const int r = w*32 + i*8 + lr;
      gload16(ksl + (size_t)(kt + r)*DH + gsrc*8, klds + (w*32 + i*8)*64);
    }
    __syncthreads();
    #pragma unroll
    for (int n = 0; n < 8; ++n){
      f32x4 s = (f32x4){0.f,0.f,0.f,0.f};
      #pragma unroll
      for (int ks = 0; ks < 2; ++ks){
        const int krow = n*16 + c16;
        bf16x8 kf = *(const bf16x8*)(klds + krow*64 + ((ks*4 + g) ^ (krow & 7))*8);
        s = __builtin_amdgcn_mfma_f32_16x16x32_bf16(kf, qf[ks], s, 0, 0, 0);
      }
      #pragma unroll
      for (int r = 0; r < 4; ++r) sum += __expf(s[r]*sc);
    }
    __syncthreads();
  }
  sum += __shfl_xor(sum, 16, 64);
  sum += __shfl_xor(sum, 32, 64);
  const float inv = 1.0f/sum;

  f32x4 oacc[4];
  #pragma unroll
  for (int n2 = 0; n2 < 4; ++n2) oacc[n2] = (f32x4){0.f,0.f,0.f,0.f};

  float* dbase = dist + ((size_t)bh*S_ + q0 + c16)*S_;   // this lane's q-row

  // ---- pass 2: dist write + PV ----
  for (int kt = 0; kt < S_; kt += KBLK){
    #pragma unroll
    for (int i = 0; i < 4; ++i){
      const int r = w*32 + i*8 + lr;
      gload16(ksl + (size_t)(kt + r)*DH + gsrc*8, klds + (w*32 + i*8)*64);
    }
    #pragma unroll
    for (int i = 0; i < 4; ++i){
      const int d = w*16 + i*4 + lr4;
      const int gs = lg4 ^ (d & 15);
      gload16(vsl + (size_t)d*S_ + kt + gs*8, vtlds + (w*16 + i*4)*128);
    }
    __syncthreads();
    #pragma unroll
    for (int n = 0; n < 8; ++n){
      f32x4 s = (f32x4){0.f,0.f,0.f,0.f};
      #pragma unroll
      for (int ks = 0; ks < 2; ++ks){
        const int krow = n*16 + c16;
        bf16x8 kf = *(const bf16x8*)(klds + krow*64 + ((ks*4 + g) ^ (krow & 7))*8);
        s = __builtin_amdgcn_mfma_f32_16x16x32_bf16(kf, qf[ks], s, 0, 0, 0);
      }
      float p0 = __expf(s[0]*sc)*inv, p1 = __expf(s[1]*sc)*inv;
      float p2 = __expf(s[2]*sc)*inv, p3 = __expf(s[3]*sc)*inv;
      // dist: lane writes 4 contiguous cols of its own q-row
      float4 pv; pv.x = p0; pv.y = p1; pv.z = p2; pv.w = p3;
      *(float4*)(dbase + kt + n*16 + g*4) = pv;
      // P -> plds (bf16), 8B store, swizzled
      const int col = n*16 + g*4;
      const int slot = (col >> 3) ^ c16;
      unsigned lo = (unsigned)f2bf(p0) | ((unsigned)f2bf(p1) << 16);
      unsigned hi = (unsigned)f2bf(p2) | ((unsigned)f2bf(p3) << 16);
      uint2 pk2; pk2.x = lo; pk2.y = hi;
      *(uint2*)(plds + w*2048 + c16*128 + slot*8 + (g & 1)*4) = pk2;
    }
    // PV: oacc += P @ V^T-rows
    #pragma unroll
    for (int kc = 0; kc < 4; ++kc){
      bf16x8 pf = *(const bf16x8*)(plds + w*2048 + c16*128 + ((kc*4 + g) ^ c16)*8);
      #pragma unroll
      for (int n2 = 0; n2 < 4; ++n2){
        const int d = n2*16 + c16;
        bf16x8 vf = *(const bf16x8*)(vtlds + d*128 + ((kc*4 + g) ^ (d & 15))*8);
        oacc[n2] = __builtin_amdgcn_mfma_f32_16x16x32_bf16(pf, vf, oacc[n2], 0, 0, 0);
      }
    }
    __syncthreads();
  }

  u16* asl = attnb + (size_t)bh*S_*DH;
  #pragma unroll
  for (int n2 = 0; n2 < 4; ++n2)
    #pragma unroll
    for (int r = 0; r < 4; ++r)
      asl[(size_t)(q0 + g*4 + r)*DH + n2*16 + c16] = f2bf(oacc[n2][r]);
}

// ---------------- launch ----------------
extern "C" void kernel_launch(void* const* d_in, const int* in_sizes, int n_in,
                              void* d_out, int out_size, void* d_ws, size_t ws_size,
                              hipStream_t stream)
{
  const float* Q  = (const float*)d_in[0];
  const float* K  = (const float*)d_in[1];
  const float* V  = (const float*)d_in[2];
  const float* WQ = (const float*)d_in[3]; const float* bQ = (const float*)d_in[4];
  const float* WK = (const float*)d_in[5]; const float* bK = (const float*)d_in[6];
  const float* WV = (const float*)d_in[7]; const float* bV = (const float*)d_in[8];
  const float* WO = (const float*)d_in[9]; const float* bO = (const float*)d_in[10];

  float* out  = (float*)d_out;
  float* dist = out + (size_t)BS_*D_;

  char* ws = (char*)d_ws;
  u16* qb    = (u16*)(ws);
  u16* kb    = (u16*)(ws + (8u<<20));
  u16* vb    = (u16*)(ws + (16u<<20));
  u16* vtb   = (u16*)(ws + (24u<<20));
  u16* attnb = (u16*)(ws + (32u<<20));
  u16* Qc    = (u16*)(ws + (40u<<20));
  u16* Kc    = (u16*)(ws + (48u<<20));
  u16* Vc    = (u16*)(ws + (56u<<20));
  u16* wqb   = (u16*)(ws + (64u<<20));
  u16* wkb   = (u16*)(ws + (66u<<20));
  u16* wvb   = (u16*)(ws + (68u<<20));
  u16* wob   = (u16*)(ws + (70u<<20));

  cvt_kernel<<<8192, 256, 0, stream>>>(Q, K, V, WQ, WK, WV, WO,
                                       Qc, Kc, Vc, wqb, wkb, wvb, wob);

  dim3 gp(D_/64, BS_/128);                 // (16, 32)
  gemm_kernel<0><<<gp, 256, 0, stream>>>(Qc, wqb, bQ, qb, BS_, D_, D_);
  gemm_kernel<0><<<gp, 256, 0, stream>>>(Kc, wkb, bK, kb, BS_, D_, D_);
  gemm_kernel<0><<<gp, 256, 0, stream>>>(Vc, wvb, bV, vb, BS_, D_, D_);

  vtrans_kernel<<<dim3(S_/64, B_*H_), 256, 0, stream>>>(vb, vtb);

  attn_kernel<<<dim3(S_/QBLK, B_*H_), 256, 0, stream>>>(qb, kb, vtb, dist, attnb);

  gemm_kernel<1><<<gp, 256, 0, stream>>>(attnb, wob, bO, out, BS_, D_, D_);
}

// Round 3
// 316.459 us; speedup vs baseline: 2.0055x; 1.0007x over previous
//
#include <hip/hip_runtime.h>
#include <stdint.h>

#define B_ 2
#define S_ 2048
#define D_ 1024
#define H_ 16
#define DH 64
#define BS_ (B_*S_)
#define QBLK 64
#define KBLK 128

typedef unsigned short u16;
typedef __attribute__((ext_vector_type(8))) __bf16 bf16x8;
typedef __attribute__((ext_vector_type(4))) float f32x4;

__device__ __forceinline__ u16 f2bf(float f){
  unsigned u = __float_as_uint(f);
  u += 0x7fffu + ((u >> 16) & 1u);   // RNE
  return (u16)(u >> 16);
}

union pk8 { u16 a[8]; uint4 v; };

typedef __attribute__((address_space(1))) const unsigned gas_u32;
typedef __attribute__((address_space(3))) unsigned las_u32;
__device__ __forceinline__ void gload16(const void* g, void* l){
  __builtin_amdgcn_global_load_lds((gas_u32*)g, (las_u32*)l, 16, 0, 0);
}

// ---------------- fp32 -> bf16 bulk convert (7 tensors) ----------------
__global__ __launch_bounds__(256) void cvt_kernel(
    const float* __restrict__ Q, const float* __restrict__ K, const float* __restrict__ V,
    const float* __restrict__ WQ, const float* __restrict__ WK,
    const float* __restrict__ WV, const float* __restrict__ WO,
    u16* Qc, u16* Kc, u16* Vc, u16* wq, u16* wk, u16* wv, u16* wo)
{
  const int b = blockIdx.x;
  const float* s; u16* d; size_t off;
  if (b < 6144){
    int t = b >> 11;
    s = t==0?Q:(t==1?K:V); d = t==0?Qc:(t==1?Kc:Vc);
    off = (size_t)(b & 2047)*2048;
  } else {
    int t = (b - 6144) >> 9;
    s = t==0?WQ:(t==1?WK:(t==2?WV:WO)); d = t==0?wq:(t==1?wk:(t==2?wv:wo));
    off = (size_t)((b - 6144) & 511)*2048;
  }
  const float* sp = s + off + (size_t)threadIdx.x*8;
  float4 v0 = *(const float4*)sp, v1 = *(const float4*)(sp + 4);
  pk8 p;
  p.a[0]=f2bf(v0.x); p.a[1]=f2bf(v0.y); p.a[2]=f2bf(v0.z); p.a[3]=f2bf(v0.w);
  p.a[4]=f2bf(v1.x); p.a[5]=f2bf(v1.y); p.a[6]=f2bf(v1.z); p.a[7]=f2bf(v1.w);
  *(uint4*)(d + off + (size_t)threadIdx.x*8) = p.v;
}

// ---------------- GEMM: C[M,N] = A[M,K](bf16) @ W[N,K]^T(bf16) + bias ----------------
// BM=128, BN=64, BK=64, 4 waves (2x2), global_load_lds, XOR-swizzled LDS,
// double-buffered 2-phase pipeline (stage t+1 before compute t).
template<int F32OUT>
__global__ __launch_bounds__(256) void gemm_kernel(
    const u16* __restrict__ A, const u16* __restrict__ Wt,
    const float* __restrict__ bias, void* __restrict__ Cout,
    int M, int N, int K)
{
  const int bn = blockIdx.x, bm = blockIdx.y;
  const int tid = threadIdx.x, w = tid >> 6, lane = tid & 63;
  const int g = lane >> 4, c16 = lane & 15;
  const int wr = w >> 1, wc = w & 1;
  const int lr = lane >> 3, lg = lane & 7;
  const int gsrc = lg ^ (lr & 7);          // inverse-swizzled source granule

  __shared__ alignas(16) u16 at[2][128*64];
  __shared__ alignas(16) u16 bt[2][64*64];

  f32x4 acc[4][2];
  #pragma unroll
  for (int mi = 0; mi < 4; ++mi)
    #pragma unroll
    for (int ni = 0; ni < 2; ++ni) acc[mi][ni] = (f32x4){0.f,0.f,0.f,0.f};

  auto stage = [&](int buf, int kt){
    #pragma unroll
    for (int i = 0; i < 4; ++i){
      const int r = w*32 + i*8 + lr;
      gload16(A + (size_t)(bm*128 + r)*K + kt + gsrc*8, at[buf] + (w*32 + i*8)*64);
    }
    #pragma unroll
    for (int i = 0; i < 2; ++i){
      const int r = w*16 + i*8 + lr;
      gload16(Wt + (size_t)(bn*64 + r)*K + kt + gsrc*8, bt[buf] + (w*16 + i*8)*64);
    }
  };

  stage(0, 0);
  __syncthreads();
  int cur = 0;
  for (int kt = 0; kt < K; kt += 64){
    if (kt + 64 < K) stage(cur ^ 1, kt + 64);
    #pragma unroll
    for (int ks = 0; ks < 2; ++ks){
      bf16x8 af[4], bfr[2];
      #pragma unroll
      for (int mi = 0; mi < 4; ++mi){
        const int row = wr*64 + mi*16 + c16;
        af[mi] = *(const bf16x8*)(at[cur] + row*64 + ((ks*4 + g) ^ (row & 7))*8);
      }
      #pragma unroll
      for (int ni = 0; ni < 2; ++ni){
        const int row = wc*32 + ni*16 + c16;
        bfr[ni] = *(const bf16x8*)(bt[cur] + row*64 + ((ks*4 + g) ^ (row & 7))*8);
      }
      #pragma unroll
      for (int mi = 0; mi < 4; ++mi)
        #pragma unroll
        for (int ni = 0; ni < 2; ++ni)
          acc[mi][ni] = __builtin_amdgcn_mfma_f32_16x16x32_bf16(
              af[mi], bfr[ni], acc[mi][ni], 0, 0, 0);
    }
    __syncthreads();
    cur ^= 1;
  }

  #pragma unroll
  for (int mi = 0; mi < 4; ++mi){
    const int row0 = bm*128 + wr*64 + mi*16 + g*4;
    #pragma unroll
    for (int ni = 0; ni < 2; ++ni){
      const int col = bn*64 + wc*32 + ni*16 + c16;
      const float bb = bias[col];
      #pragma unroll
      for (int r = 0; r < 4; ++r){
        float v = acc[mi][ni][r] + bb;
        if (F32OUT) ((float*)Cout)[(size_t)(row0 + r)*N + col] = v;
        else        ((u16*)Cout)[(size_t)(row0 + r)*N + col] = f2bf(v);
      }
    }
  }
}

// ---------------- per-head V transpose: vtb[bh][d][k] = vb[bh][k][d] ----------------
__global__ __launch_bounds__(256) void vtrans_kernel(
    const u16* __restrict__ vb, u16* __restrict__ vtb)
{
  const int kt = blockIdx.x, bh = blockIdx.y;
  __shared__ alignas(16) u16 t[64][80];
  const int tid = threadIdx.x;
  const u16* slab = vb + (size_t)bh*S_*DH + (size_t)kt*64*DH;
  #pragma unroll
  for (int j = 0; j < 2; ++j){
    const int r = j*32 + (tid >> 3), c = (tid & 7)*8;
    *(bf16x8*)(&t[r][c]) = *(const bf16x8*)(slab + (size_t)r*DH + c);
  }
  __syncthreads();
  u16* oslab = vtb + (size_t)bh*DH*S_ + (size_t)kt*64;
  #pragma unroll
  for (int j = 0; j < 2; ++j){
    const int dd = j*32 + (tid >> 3), k8 = (tid & 7)*8;
    pk8 u;
    #pragma unroll
    for (int e = 0; e < 8; ++e) u.a[e] = t[k8 + e][dd];
    *(uint4*)(oslab + (size_t)dd*S_ + k8) = u.v;
  }
}

// ---------------- fused attention, swapped-S, double-buffered staging --------
__global__ __launch_bounds__(256) void attn_kernel(
    const u16* __restrict__ qb, const u16* __restrict__ kb,
    const u16* __restrict__ vtb, float* __restrict__ dist,
    u16* __restrict__ attnb)
{
  const int qblk = blockIdx.x, bh = blockIdx.y;
  const int tid = threadIdx.x, w = tid >> 6, lane = tid & 63;
  const int g = lane >> 4, c16 = lane & 15;
  const int lr = lane >> 3, lg = lane & 7;
  const int gsrc = lg ^ (lr & 7);
  const int lr4 = lane >> 4, lg4 = lane & 15;

  __shared__ alignas(16) u16 klds[2][128*64];    // 2 x 16 KB
  __shared__ alignas(16) u16 vtlds[2][64*128];   // 2 x 16 KB
  __shared__ alignas(16) u16 plds[4*16*128];     // 16 KB

  const u16* qsl = qb  + (size_t)bh*S_*DH;
  const u16* ksl = kb  + (size_t)bh*S_*DH;
  const u16* vsl = vtb + (size_t)bh*DH*S_;

  const int q0 = qblk*QBLK + w*16;
  bf16x8 qf[2];
  #pragma unroll
  for (int ks = 0; ks < 2; ++ks)
    qf[ks] = *(const bf16x8*)(qsl + (size_t)(q0 + c16)*DH + ks*32 + g*8);

  const float sc = 1.0f/32.0f;
  float sum = 0.f;

  auto stageK = [&](int buf, int kt){
    #pragma unroll
    for (int i = 0; i < 4; ++i){
      const int r = w*32 + i*8 + lr;
      gload16(ksl + (size_t)(kt + r)*DH + gsrc*8, klds[buf] + (w*32 + i*8)*64);
    }
  };
  auto stageV = [&](int buf, int kt){
    #pragma unroll
    for (int i = 0; i < 4; ++i){
      const int d = w*16 + i*4 + lr4;
      const int gs = lg4 ^ (d & 15);
      gload16(vsl + (size_t)d*S_ + kt + gs*8, vtlds[buf] + (w*16 + i*4)*128);
    }
  };

  // ---- pass 1: denominators (K tiles only), 2-phase dbuf ----
  stageK(0, 0);
  __syncthreads();
  int cur = 0;
  for (int kt = 0; kt < S_; kt += KBLK){
    if (kt + KBLK < S_) stageK(cur ^ 1, kt + KBLK);
    __builtin_amdgcn_s_setprio(1);
    #pragma unroll
    for (int n = 0; n < 8; ++n){
      f32x4 s = (f32x4){0.f,0.f,0.f,0.f};
      #pragma unroll
      for (int ks = 0; ks < 2; ++ks){
        const int krow = n*16 + c16;
        bf16x8 kf = *(const bf16x8*)(klds[cur] + krow*64 + ((ks*4 + g) ^ (krow & 7))*8);
        s = __builtin_amdgcn_mfma_f32_16x16x32_bf16(kf, qf[ks], s, 0, 0, 0);
      }
      __builtin_amdgcn_s_setprio(0);
      #pragma unroll
      for (int r = 0; r < 4; ++r) sum += __expf(s[r]*sc);
      __builtin_amdgcn_s_setprio(1);
    }
    __builtin_amdgcn_s_setprio(0);
    __syncthreads();
    cur ^= 1;
  }
  sum += __shfl_xor(sum, 16, 64);
  sum += __shfl_xor(sum, 32, 64);
  const float inv = 1.0f/sum;

  f32x4 oacc[4];
  #pragma unroll
  for (int n2 = 0; n2 < 4; ++n2) oacc[n2] = (f32x4){0.f,0.f,0.f,0.f};

  float* dbase = dist + ((size_t)bh*S_ + q0 + c16)*S_;   // this lane's q-row

  // ---- pass 2: dist write + PV, 2-phase dbuf ----
  stageK(0, 0);
  stageV(0, 0);
  __syncthreads();
  cur = 0;
  for (int kt = 0; kt < S_; kt += KBLK){
    if (kt + KBLK < S_){ stageK(cur ^ 1, kt + KBLK); stageV(cur ^ 1, kt + KBLK); }
    #pragma unroll
    for (int n = 0; n < 8; ++n){
      f32x4 s = (f32x4){0.f,0.f,0.f,0.f};
      __builtin_amdgcn_s_setprio(1);
      #pragma unroll
      for (int ks = 0; ks < 2; ++ks){
        const int krow = n*16 + c16;
        bf16x8 kf = *(const bf16x8*)(klds[cur] + krow*64 + ((ks*4 + g) ^ (krow & 7))*8);
        s = __builtin_amdgcn_mfma_f32_16x16x32_bf16(kf, qf[ks], s, 0, 0, 0);
      }
      __builtin_amdgcn_s_setprio(0);
      float p0 = __expf(s[0]*sc)*inv, p1 = __expf(s[1]*sc)*inv;
      float p2 = __expf(s[2]*sc)*inv, p3 = __expf(s[3]*sc)*inv;
      float4 pv; pv.x = p0; pv.y = p1; pv.z = p2; pv.w = p3;
      *(float4*)(dbase + kt + n*16 + g*4) = pv;
      const int col = n*16 + g*4;
      const int slot = (col >> 3) ^ c16;
      unsigned lo = (unsigned)f2bf(p0) | ((unsigned)f2bf(p1) << 16);
      unsigned hi = (unsigned)f2bf(p2) | ((unsigned)f2bf(p3) << 16);
      uint2 pk2; pk2.x = lo; pk2.y = hi;
      *(uint2*)(plds + w*2048 + c16*128 + slot*8 + (g & 1)*4) = pk2;
    }
    __builtin_amdgcn_s_setprio(1);
    #pragma unroll
    for (int kc = 0; kc < 4; ++kc){
      bf16x8 pf = *(const bf16x8*)(plds + w*2048 + c16*128 + ((kc*4 + g) ^ c16)*8);
      #pragma unroll
      for (int n2 = 0; n2 < 4; ++n2){
        const int d = n2*16 + c16;
        bf16x8 vf = *(const bf16x8*)(vtlds[cur] + d*128 + ((kc*4 + g) ^ (d & 15))*8);
        oacc[n2] = __builtin_amdgcn_mfma_f32_16x16x32_bf16(pf, vf, oacc[n2], 0, 0, 0);
      }
    }
    __builtin_amdgcn_s_setprio(0);
    __syncthreads();
    cur ^= 1;
  }

  u16* asl = attnb + (size_t)bh*S_*DH;
  #pragma unroll
  for (int n2 = 0; n2 < 4; ++n2)
    #pragma unroll
    for (int r = 0; r < 4; ++r)
      asl[(size_t)(q0 + g*4 + r)*DH + n2*16 + c16] = f2bf(oacc[n2][r]);
}

// ---------------- launch ----------------
extern "C" void kernel_launch(void* const* d_in, const int* in_sizes, int n_in,
                              void* d_out, int out_size, void* d_ws, size_t ws_size,
                              hipStream_t stream)
{
  const float* Q  = (const float*)d_in[0];
  const float* K  = (const float*)d_in[1];
  const float* V  = (const float*)d_in[2];
  const float* WQ = (const float*)d_in[3]; const float* bQ = (const float*)d_in[4];
  const float* WK = (const float*)d_in[5]; const float* bK = (const float*)d_in[6];
  const float* WV = (const float*)d_in[7]; const float* bV = (const float*)d_in[8];
  const float* WO = (const float*)d_in[9]; const float* bO = (const float*)d_in[10];

  float* out  = (float*)d_out;
  float* dist = out + (size_t)BS_*D_;

  char* ws = (char*)d_ws;
  u16* qb    = (u16*)(ws);
  u16* kb    = (u16*)(ws + (8u<<20));
  u16* vb    = (u16*)(ws + (16u<<20));
  u16* vtb   = (u16*)(ws + (24u<<20));
  u16* attnb = (u16*)(ws + (32u<<20));
  u16* Qc    = (u16*)(ws + (40u<<20));
  u16* Kc    = (u16*)(ws + (48u<<20));
  u16* Vc    = (u16*)(ws + (56u<<20));
  u16* wqb   = (u16*)(ws + (64u<<20));
  u16* wkb   = (u16*)(ws + (66u<<20));
  u16* wvb   = (u16*)(ws + (68u<<20));
  u16* wob   = (u16*)(ws + (70u<<20));

  cvt_kernel<<<8192, 256, 0, stream>>>(Q, K, V, WQ, WK, WV, WO,
                                       Qc, Kc, Vc, wqb, wkb, wvb, wob);

  dim3 gp(D_/64, BS_/128);                 // (16, 32)
  gemm_kernel<0><<<gp, 256, 0, stream>>>(Qc, wqb, bQ, qb, BS_, D_, D_);
  gemm_kernel<0><<<gp, 256, 0, stream>>>(Kc, wkb, bK, kb, BS_, D_, D_);
  gemm_kernel<0><<<gp, 256, 0, stream>>>(Vc, wvb, bV, vb, BS_, D_, D_);

  vtrans_kernel<<<dim3(S_/64, B_*H_), 256, 0, stream>>>(vb, vtb);

  attn_kernel<<<dim3(S_/QBLK, B_*H_), 256, 0, stream>>>(qb, kb, vtb, dist, attnb);

  gemm_kernel<1><<<gp, 256, 0, stream>>>(attnb, wob, bO, out, BS_, D_, D_);
}